// Round 7
// baseline (62.995 us; speedup 1.0000x reference)
//
#include <hip/hip_runtime.h>

typedef __attribute__((ext_vector_type(8))) short bf16x8;
typedef __attribute__((ext_vector_type(4))) float f32x4;

#define EPSV 1e-5f
// (1/TEMP) * log2(e),  TEMP = 0.5  -> exp2-domain scale
#define SCALE 2.885390081777927f

// Must be the builtin — raw inline-asm v_exp_f32 lacks the TRANS-pipe hazard
// nop (asm is opaque to the hazard recognizer) and returns garbage (R4).
__device__ __forceinline__ float fast_exp2(float x) { return __builtin_amdgcn_exp2f(x); }

// async global->LDS DMA, 16 B per lane; LDS dest = uniform base + lane*16.
__device__ __forceinline__ void dma16(const void* g, void* l) {
  __builtin_amdgcn_global_load_lds(
      (const __attribute__((address_space(1))) unsigned*)g,
      (__attribute__((address_space(3))) unsigned*)l, 16, 0, 0);
}

__device__ __forceinline__ ushort f32_to_bf16(float f) {
  union { float f; unsigned u; } cv; cv.f = f;
  unsigned u = cv.u;
  u += 0x7FFFu + ((u >> 16) & 1u);   // round-to-nearest-even
  return (ushort)(u >> 16);
}

// ---------------------------------------------------------------------------
// Packed bank layout (bf16, pre-scaled by SCALE), designed so the main kernel's
// DMA is contiguous and its ds_reads are conflict-free:
//   col-tile ct = col>>4 (16 cols each), r16 = col&15; channel c: ks = c>>5,
//   kg = (c>>3)&3, b = c&7.
//   byte addr = ct*8192 + ks*1024 + kg*256 + r16*16 + b*2
// ---------------------------------------------------------------------------

// ---------------------------------------------------------------------------
// Fused prep kernel, grid = 512 + 512 + 64 = 1088 blocks, 256 threads.
//  [0,512):   pack anchors  [B,C,H,W] f32 -> Apk[p][n][c] bf16 (coalesced via
//             LDS transpose) + pos-pair dot posDot[p*64+n] (f32)
//  [512,1024): per-patch label mean -> flags
//  [1024,1088): bank repack [L,C,8,8] f32 -> packed tile layout above
// ---------------------------------------------------------------------------
__global__ __launch_bounds__(256) void cpl_prep(
    const float* __restrict__ mainO, const float* __restrict__ emaO,
    const float* __restrict__ label, const float* __restrict__ negB,
    const float* __restrict__ posB,
    ushort* __restrict__ Apk, float* __restrict__ posDot,
    int* __restrict__ flags, ushort* __restrict__ bankN, ushort* __restrict__ bankP)
{
  __shared__ ushort shU[64 * 256];   // 32 KiB
  __shared__ float  shF[4][64];
  const int bid = blockIdx.x;
  const int t = threadIdx.x;

  if (bid < 512) {
    // ---- anchor pack + pos dot: block = (b, y) ----
    const int b = bid >> 6, y = bid & 63;
    const int cg = t >> 4;            // c-offset 0..15
    const int x4 = t & 15;            // float4 index along W
    const float* mB = mainO + (((size_t)b * 256 + cg) * 64 + y) * 64 + x4 * 4;
    const float* eB = emaO  + (((size_t)b * 256 + cg) * 64 + y) * 64 + x4 * 4;
    float4 acc4 = make_float4(0.f, 0.f, 0.f, 0.f);
#pragma unroll
    for (int pass = 0; pass < 16; ++pass) {
      const int c = pass * 16 + cg;
      const float4 mv = *(const float4*)(mB + (size_t)pass * 16 * 4096);
      const float4 ev = *(const float4*)(eB + (size_t)pass * 16 * 4096);
      acc4.x += mv.x * ev.x; acc4.y += mv.y * ev.y;
      acc4.z += mv.z * ev.z; acc4.w += mv.w * ev.w;
      const float vals[4] = {mv.x, mv.y, mv.z, mv.w};
#pragma unroll
      for (int j = 0; j < 4; ++j) {
        const int x = x4 * 4 + j;
        shU[x * 256 + (c ^ ((x & 7) << 3))] = f32_to_bf16(vals[j]);
      }
    }
    // reduce pos partials over c-groups (cg bit0 = lane bit4, bit1 = lane bit5)
    acc4.x += __shfl_xor(acc4.x, 16, 64); acc4.y += __shfl_xor(acc4.y, 16, 64);
    acc4.z += __shfl_xor(acc4.z, 16, 64); acc4.w += __shfl_xor(acc4.w, 16, 64);
    acc4.x += __shfl_xor(acc4.x, 32, 64); acc4.y += __shfl_xor(acc4.y, 32, 64);
    acc4.z += __shfl_xor(acc4.z, 32, 64); acc4.w += __shfl_xor(acc4.w, 32, 64);
    if ((t & 63) < 16) *(float4*)&shF[t >> 6][(t & 15) * 4] = acc4;
    __syncthreads();
    // write packed anchors (coalesced b128)
#pragma unroll
    for (int it = 0; it < 8; ++it) {
      const int lin = it * 256 + t;          // 0..2047
      const int x = lin >> 5, c8 = lin & 31;
      const uint4 v = *(const uint4*)&shU[x * 256 + ((c8 * 8) ^ ((x & 7) << 3))];
      const int p = b * 64 + ((y >> 3) << 3) + (x >> 3);
      const int n = ((y & 7) << 3) + (x & 7);
      *(uint4*)&Apk[((size_t)p * 64 + n) * 256 + c8 * 8] = v;
    }
    if (t < 64) {
      const float pv = shF[0][t] + shF[1][t] + shF[2][t] + shF[3][t];
      const int p = b * 64 + ((y >> 3) << 3) + (t >> 3);
      const int n = ((y & 7) << 3) + (t & 7);
      posDot[p * 64 + n] = pv;
    }
  } else if (bid < 1024) {
    // ---- label mean -> flag ----
    const int p = bid - 512;
    const int b = p >> 6, pj = (p >> 3) & 7, pk = p & 7;
    const size_t base = ((size_t)b * 256 + pj * 32) * 256 + pk * 32;
    float s = 0.f;
#pragma unroll
    for (int i = 0; i < 4; ++i) {
      const int e = t * 4 + i;               // 0..1023, r=e>>5, cc=e&31
      s += label[base + (size_t)(e >> 5) * 256 + (e & 31)];
    }
#pragma unroll
    for (int d = 1; d < 64; d <<= 1) s += __shfl_xor(s, d, 64);
    if ((t & 63) == 0) shF[0][t >> 6] = s;
    __syncthreads();
    if (t == 0)
      flags[p] = ((shF[0][0] + shF[0][1] + shF[0][2] + shF[0][3]) * (1.f / 1024.f) < 0.1f) ? 1 : 0;
  } else {
    // ---- bank repack (pre-scaled by SCALE) into the packed tile layout ----
    const int bb = bid - 1024;
    const float* src = (bb < 32 ? negB : posB) + (size_t)(bb & 31) * 16384;
    ushort* dst = (bb < 32 ? bankN : bankP) + (size_t)(bb & 31) * 16384;
#pragma unroll 8
    for (int it = 0; it < 64; ++it) {
      const int lin = it * 256 + t;          // [c][posi] linear, coalesced read
      const int c = lin >> 6, posi = lin & 63;
      shU[(posi * 256 + c) ^ ((posi & 31) << 1)] = f32_to_bf16(src[lin] * SCALE);
    }
    __syncthreads();
    unsigned* dst32 = (unsigned*)dst;        // 8192 uints per slab
#pragma unroll 8
    for (int it = 0; it < 32; ++it) {
      const int pt = it >> 3, ks = it & 7;
      const int kg = t >> 6, r16 = (t >> 2) & 15, bw = t & 3;
      const int posi = pt * 16 + r16;
      const int c = ks * 32 + kg * 8 + bw * 2;
      const unsigned v = *(const unsigned*)&shU[(posi * 256 + c) ^ ((posi & 31) << 1)];
      dst32[pt * 2048 + ks * 256 + kg * 64 + r16 * 4 + bw] = v;
    }
  }
}

// ---------------------------------------------------------------------------
// Main kernel: grid=512 (one patch each), block=256 (4 waves).
// A fragments pinned in registers. B staged into PER-WAVE-PRIVATE LDS double
// buffers via global_load_lds; packed bank layout makes each DMA instruction
// a contiguous 1 KB read AND each ds_read_b128 16-lane group contiguous
// (conflict-free). Counted s_waitcnt vmcnt(8), no __syncthreads in the loop.
// ---------------------------------------------------------------------------
__global__ __launch_bounds__(256, 2) void cpl_main(
    const ushort* __restrict__ Apk, const float* __restrict__ posDot,
    const ushort* __restrict__ bankN, const ushort* __restrict__ bankP,
    const int* __restrict__ flags, float* __restrict__ blockSums)
{
  __shared__ __align__(1024) char Bsm[4 * 2 * 8192];   // 64 KiB: wave-private dbuf
  __shared__ float posNeg[64];
  __shared__ float swS[4][64];

  const int p = blockIdx.x;
  const int t = threadIdx.x;
  const int l = t & 63, w = t >> 6;
  const int r16 = l & 15, kg = l >> 4;

  if (t < 64) posNeg[t] = -posDot[p * 64 + t] * SCALE;

  const char* bankB = (const char*)(flags[p] ? bankP : bankN);
  char* wlds = Bsm + w * 16384;

#define ISSUE(BUF, NT) do {                                                        \
    const char* g0_ = bankB + (((size_t)(w * 32 + (NT))) << 13) + l * 16;          \
    char* l0_ = wlds + (BUF) * 8192;                                               \
    _Pragma("unroll") for (int i = 0; i < 8; ++i)                                  \
      dma16(g0_ + i * 1024, l0_ + i * 1024);                                       \
  } while (0)

  // prefetch tiles 0 and 1 (16 DMAs outstanding)
  ISSUE(0, 0);
  ISSUE(1, 1);

  __syncthreads();   // posNeg ready

  // ---- A fragments: lane l holds A[mt*16+(l&15)][ks*32+(l>>4)*8 + 0..7] ----
  const ushort* Ab = Apk + (size_t)p * 16384;
  bf16x8 afrag[4][8];
#pragma unroll
  for (int mt = 0; mt < 4; ++mt)
#pragma unroll
    for (int ks = 0; ks < 8; ++ks)
      afrag[mt][ks] = *(const bf16x8*)(Ab + (mt * 16 + r16) * 256 + ks * 32 + kg * 8);
#pragma unroll
  for (int mt = 0; mt < 4; ++mt)
#pragma unroll
    for (int ks = 0; ks < 8; ++ks)
      asm volatile("" : "+v"(afrag[mt][ks]));

  float s[16];
#pragma unroll
  for (int e = 0; e < 16; ++e) s[e] = 0.f;

  f32x4 acc[4];
  // conflict-free read base: 16-lane group reads 256 contiguous bytes
  const char* rbase = wlds + kg * 256 + r16 * 16;

#define WAITV8() do { asm volatile("s_waitcnt vmcnt(8)" ::: "memory");             \
                      __builtin_amdgcn_sched_barrier(0); } while (0)
#define WAITV0() do { asm volatile("s_waitcnt vmcnt(0)" ::: "memory");             \
                      __builtin_amdgcn_sched_barrier(0); } while (0)

#define MFMA_TILE(BUF) do {                                                        \
    const char* rb_ = rbase + (BUF) * 8192;                                        \
    bf16x8 bfrag[8];                                                               \
    _Pragma("unroll") for (int ks = 0; ks < 8; ++ks)                               \
      bfrag[ks] = *(const bf16x8*)(rb_ + ks * 1024);                               \
    _Pragma("unroll") for (int mt = 0; mt < 4; ++mt)                               \
      acc[mt] = *(const f32x4*)&posNeg[mt * 16 + kg * 4];                          \
    _Pragma("unroll") for (int ks = 0; ks < 8; ++ks)                               \
      _Pragma("unroll") for (int mt = 0; mt < 4; ++mt)                             \
        acc[mt] = __builtin_amdgcn_mfma_f32_16x16x32_bf16(afrag[mt][ks],           \
                      bfrag[ks], acc[mt], 0, 0, 0);                                \
  } while (0)

#define EXPACC() do {                                                              \
    _Pragma("unroll") for (int mt = 0; mt < 4; ++mt)                               \
      _Pragma("unroll") for (int i = 0; i < 4; ++i)                                \
        s[mt * 4 + i] += fast_exp2(acc[mt][i]); } while (0)

#pragma unroll 2
  for (int nt = 0; nt < 30; ++nt) {
    WAITV8();                 // tile nt's 8 DMAs (older than newest 8) are done
    MFMA_TILE(nt & 1);
    __builtin_amdgcn_sched_barrier(0);   // ds_reads consumed before overwrite
    ISSUE(nt & 1, nt + 2);    // refill just-consumed buffer
    EXPACC();
  }
  WAITV8();                   // tile 30 (newest 8 = tile 31's DMAs)
  MFMA_TILE(0);
  EXPACC();
  WAITV0();                   // tile 31
  MFMA_TILE(1);
  EXPACC();

#undef ISSUE
#undef WAITV8
#undef WAITV0
#undef MFMA_TILE
#undef EXPACC

  // ---- sum the 16 column-partials (lanes differing in low 4 bits) ----
#pragma unroll
  for (int d = 1; d < 16; d <<= 1)
#pragma unroll
    for (int e = 0; e < 16; ++e) s[e] += __shfl_xor(s[e], d, 64);
  if (r16 == 0) {
#pragma unroll
    for (int mt = 0; mt < 4; ++mt)
#pragma unroll
      for (int i = 0; i < 4; ++i)
        swS[w][mt * 16 + kg * 4 + i] = s[mt * 4 + i];
  }
  __syncthreads();

  // ---- final per-row loss + block reduce (wave 0 only) ----
  if (t < 64) {
    const float S = 1.f + swS[0][t] + swS[1][t] + swS[2][t] + swS[3][t];
    float loss = -logf(1.f / S + EPSV);
#pragma unroll
    for (int d = 1; d < 64; d <<= 1) loss += __shfl_xor(loss, d, 64);
    if (t == 0) blockSums[p] = loss;
  }
}

// ---------------------------------------------------------------------------
// Final: mean of 512 block sums / (512*64).  grid=1, block=256.
// ---------------------------------------------------------------------------
__global__ void cpl_final(const float* __restrict__ blockSums, float* __restrict__ out) {
  const int t = threadIdx.x;
  float s = blockSums[t] + blockSums[t + 256];
#pragma unroll
  for (int d = 1; d < 64; d <<= 1) s += __shfl_xor(s, d, 64);
  __shared__ float ps[4];
  if ((t & 63) == 0) ps[t >> 6] = s;
  __syncthreads();
  if (t == 0) out[0] = (ps[0] + ps[1] + ps[2] + ps[3]) * (1.f / 32768.f);
}

extern "C" void kernel_launch(void* const* d_in, const int* in_sizes, int n_in,
                              void* d_out, int out_size, void* d_ws, size_t ws_size,
                              hipStream_t stream) {
  const float* mainO = (const float*)d_in[0];
  const float* emaO  = (const float*)d_in[1];
  const float* label = (const float*)d_in[2];
  const float* negB  = (const float*)d_in[3];
  const float* posB  = (const float*)d_in[4];
  float* out = (float*)d_out;

  char* ws = (char*)d_ws;
  float*  blockSums = (float*)ws;                        // 2 KiB
  int*    flags     = (int*)(ws + 2048);                 // 2 KiB
  ushort* bankN     = (ushort*)(ws + 4096);              // 1 MiB
  ushort* bankP     = (ushort*)(ws + 4096 + 1048576);    // 1 MiB
  float*  posDot    = (float*)(ws + 4096 + 2097152);     // 128 KiB
  ushort* Apk       = (ushort*)(ws + 4096 + 2097152 + 131072);  // 16.78 MiB

  hipLaunchKernelGGL(cpl_prep, dim3(1088), dim3(256), 0, stream,
                     mainO, emaO, label, negB, posB, Apk, posDot, flags, bankN, bankP);
  hipLaunchKernelGGL(cpl_main, dim3(512), dim3(256), 0, stream,
                     Apk, posDot, bankN, bankP, flags, blockSums);
  hipLaunchKernelGGL(cpl_final, dim3(1), dim3(256), 0, stream, blockSums, out);
}

// Round 8
// 62.938 us; speedup vs baseline: 1.0009x; 1.0009x over previous
//
#include <hip/hip_runtime.h>

typedef __attribute__((ext_vector_type(8))) short bf16x8;
typedef __attribute__((ext_vector_type(4))) float f32x4;

#define EPSV 1e-5f
// (1/TEMP) * log2(e),  TEMP = 0.5  -> exp2-domain scale
#define SCALE 2.885390081777927f

// Must be the builtin — raw inline-asm v_exp_f32 lacks the TRANS-pipe hazard
// nop (asm is opaque to the hazard recognizer) and returns garbage (R4).
__device__ __forceinline__ float fast_exp2(float x) { return __builtin_amdgcn_exp2f(x); }

// async global->LDS DMA, 16 B per lane; LDS dest = uniform base + lane*16.
__device__ __forceinline__ void dma16(const void* g, void* l) {
  __builtin_amdgcn_global_load_lds(
      (const __attribute__((address_space(1))) unsigned*)g,
      (__attribute__((address_space(3))) unsigned*)l, 16, 0, 0);
}

__device__ __forceinline__ ushort f32_to_bf16(float f) {
  union { float f; unsigned u; } cv; cv.f = f;
  unsigned u = cv.u;
  u += 0x7FFFu + ((u >> 16) & 1u);   // round-to-nearest-even
  return (ushort)(u >> 16);
}

// ---------------------------------------------------------------------------
// Packed bank layout (bf16, pre-scaled by SCALE):
//   col-tile ct = col>>4, r16 = col&15; channel c: ks = c>>5, kg = (c>>3)&3.
//   byte addr = ct*8192 + ks*1024 + kg*256 + r16*16 + (c&7)*2
// Per wave the 512-col range is a LINEAR 256 KB stream; staged in 4 KB
// quarters (ks-half of a 16-col tile) into a 4-deep per-wave LDS ring.
// ---------------------------------------------------------------------------

// ---------------------------------------------------------------------------
// Fused prep kernel, grid = 512 + 512 + 64 = 1088 blocks, 256 threads.
// ---------------------------------------------------------------------------
__global__ __launch_bounds__(256) void cpl_prep(
    const float* __restrict__ mainO, const float* __restrict__ emaO,
    const float* __restrict__ label, const float* __restrict__ negB,
    const float* __restrict__ posB,
    ushort* __restrict__ Apk, float* __restrict__ posDot,
    int* __restrict__ flags, ushort* __restrict__ bankN, ushort* __restrict__ bankP)
{
  __shared__ ushort shU[64 * 256];   // 32 KiB
  __shared__ float  shF[4][64];
  const int bid = blockIdx.x;
  const int t = threadIdx.x;

  if (bid < 512) {
    // ---- anchor pack + pos dot: block = (b, y) ----
    const int b = bid >> 6, y = bid & 63;
    const int cg = t >> 4;            // c-offset 0..15
    const int x4 = t & 15;            // float4 index along W
    const float* mB = mainO + (((size_t)b * 256 + cg) * 64 + y) * 64 + x4 * 4;
    const float* eB = emaO  + (((size_t)b * 256 + cg) * 64 + y) * 64 + x4 * 4;
    float4 acc4 = make_float4(0.f, 0.f, 0.f, 0.f);
#pragma unroll
    for (int pass = 0; pass < 16; ++pass) {
      const int c = pass * 16 + cg;
      const float4 mv = *(const float4*)(mB + (size_t)pass * 16 * 4096);
      const float4 ev = *(const float4*)(eB + (size_t)pass * 16 * 4096);
      acc4.x += mv.x * ev.x; acc4.y += mv.y * ev.y;
      acc4.z += mv.z * ev.z; acc4.w += mv.w * ev.w;
      const float vals[4] = {mv.x, mv.y, mv.z, mv.w};
#pragma unroll
      for (int j = 0; j < 4; ++j) {
        const int x = x4 * 4 + j;
        shU[x * 256 + (c ^ ((x & 7) << 3))] = f32_to_bf16(vals[j]);
      }
    }
    // reduce pos partials over c-groups (cg bit0 = lane bit4, bit1 = lane bit5)
    acc4.x += __shfl_xor(acc4.x, 16, 64); acc4.y += __shfl_xor(acc4.y, 16, 64);
    acc4.z += __shfl_xor(acc4.z, 16, 64); acc4.w += __shfl_xor(acc4.w, 16, 64);
    acc4.x += __shfl_xor(acc4.x, 32, 64); acc4.y += __shfl_xor(acc4.y, 32, 64);
    acc4.z += __shfl_xor(acc4.z, 32, 64); acc4.w += __shfl_xor(acc4.w, 32, 64);
    if ((t & 63) < 16) *(float4*)&shF[t >> 6][(t & 15) * 4] = acc4;
    __syncthreads();
    // write packed anchors (coalesced b128)
#pragma unroll
    for (int it = 0; it < 8; ++it) {
      const int lin = it * 256 + t;          // 0..2047
      const int x = lin >> 5, c8 = lin & 31;
      const uint4 v = *(const uint4*)&shU[x * 256 + ((c8 * 8) ^ ((x & 7) << 3))];
      const int p = b * 64 + ((y >> 3) << 3) + (x >> 3);
      const int n = ((y & 7) << 3) + (x & 7);
      *(uint4*)&Apk[((size_t)p * 64 + n) * 256 + c8 * 8] = v;
    }
    if (t < 64) {
      const float pv = shF[0][t] + shF[1][t] + shF[2][t] + shF[3][t];
      const int p = b * 64 + ((y >> 3) << 3) + (t >> 3);
      const int n = ((y & 7) << 3) + (t & 7);
      posDot[p * 64 + n] = pv;
    }
  } else if (bid < 1024) {
    // ---- label mean -> flag ----
    const int p = bid - 512;
    const int b = p >> 6, pj = (p >> 3) & 7, pk = p & 7;
    const size_t base = ((size_t)b * 256 + pj * 32) * 256 + pk * 32;
    float s = 0.f;
#pragma unroll
    for (int i = 0; i < 4; ++i) {
      const int e = t * 4 + i;               // 0..1023, r=e>>5, cc=e&31
      s += label[base + (size_t)(e >> 5) * 256 + (e & 31)];
    }
#pragma unroll
    for (int d = 1; d < 64; d <<= 1) s += __shfl_xor(s, d, 64);
    if ((t & 63) == 0) shF[0][t >> 6] = s;
    __syncthreads();
    if (t == 0)
      flags[p] = ((shF[0][0] + shF[0][1] + shF[0][2] + shF[0][3]) * (1.f / 1024.f) < 0.1f) ? 1 : 0;
  } else {
    // ---- bank repack (pre-scaled by SCALE) into the packed tile layout ----
    const int bb = bid - 1024;
    const float* src = (bb < 32 ? negB : posB) + (size_t)(bb & 31) * 16384;
    ushort* dst = (bb < 32 ? bankN : bankP) + (size_t)(bb & 31) * 16384;
#pragma unroll 8
    for (int it = 0; it < 64; ++it) {
      const int lin = it * 256 + t;          // [c][posi] linear, coalesced read
      const int c = lin >> 6, posi = lin & 63;
      shU[(posi * 256 + c) ^ ((posi & 31) << 1)] = f32_to_bf16(src[lin] * SCALE);
    }
    __syncthreads();
    unsigned* dst32 = (unsigned*)dst;        // 8192 uints per slab
#pragma unroll 8
    for (int it = 0; it < 32; ++it) {
      const int pt = it >> 3, ks = it & 7;
      const int kg = t >> 6, r16 = (t >> 2) & 15, bw = t & 3;
      const int posi = pt * 16 + r16;
      const int c = ks * 32 + kg * 8 + bw * 2;
      const unsigned v = *(const unsigned*)&shU[(posi * 256 + c) ^ ((posi & 31) << 1)];
      dst32[pt * 2048 + ks * 256 + kg * 64 + r16 * 4 + bw] = v;
    }
  }
}

// ---------------------------------------------------------------------------
// Main kernel: grid=512 (one patch each), block=256 (4 waves).
// 64 quarter-tile steps, 4-deep per-wave LDS ring (4 x 4 KB), DMA issued
// FIRST in each step (3 steps of fill-ahead), exp2 co-scheduled with MFMA,
// acc init via MFMA C-operand from registers, setprio around MFMA cluster.
// ---------------------------------------------------------------------------
__global__ __launch_bounds__(256, 2) void cpl_main(
    const ushort* __restrict__ Apk, const float* __restrict__ posDot,
    const ushort* __restrict__ bankN, const ushort* __restrict__ bankP,
    const int* __restrict__ flags, float* __restrict__ blockSums)
{
  __shared__ __align__(1024) char Bsm[4 * 16384];   // 64 KiB: 4 waves x 4-deep ring
  __shared__ float posLds[64];
  __shared__ float swS[4][64];

  const int p = blockIdx.x;
  const int t = threadIdx.x;
  const int l = t & 63, w = t >> 6;
  const int r16 = l & 15, kg = l >> 4;

  if (t < 64) posLds[t] = -posDot[p * 64 + t] * SCALE;

  const char* bankB = (const char*)(flags[p] ? bankP : bankN);
  const char* wsrc = bankB + (size_t)w * 262144;     // wave's 512-col stream
  char* wlds = Bsm + w * 16384;
  const int lofs = l * 16;

#define ISSUEQ(QQ, BUF) do {                                                       \
    const char* g0_ = wsrc + (QQ) * 4096 + lofs;                                   \
    char* l0_ = wlds + (BUF) * 4096;                                               \
    _Pragma("unroll") for (int i = 0; i < 4; ++i)                                  \
      dma16(g0_ + i * 1024, l0_ + i * 1024);                                       \
  } while (0)

  // prologue: 3 quarters in flight (12 DMAs)
  ISSUEQ(0, 0); ISSUEQ(1, 1); ISSUEQ(2, 2);

  __syncthreads();   // posLds ready

  // ---- A fragments: lane l holds A[mt*16+(l&15)][ks*32+(l>>4)*8 + 0..7] ----
  const ushort* Ab = Apk + (size_t)p * 16384;
  bf16x8 afrag[4][8];
#pragma unroll
  for (int mt = 0; mt < 4; ++mt)
#pragma unroll
    for (int ks = 0; ks < 8; ++ks)
      afrag[mt][ks] = *(const bf16x8*)(Ab + (mt * 16 + r16) * 256 + ks * 32 + kg * 8);
#pragma unroll
  for (int mt = 0; mt < 4; ++mt)
#pragma unroll
    for (int ks = 0; ks < 8; ++ks)
      asm volatile("" : "+v"(afrag[mt][ks]));

  // per-lane -pos2 init in REGISTERS (row = mt*16 + kg*4 + i)
  f32x4 negInit[4];
#pragma unroll
  for (int mt = 0; mt < 4; ++mt) negInit[mt] = *(const f32x4*)&posLds[mt * 16 + kg * 4];
#pragma unroll
  for (int mt = 0; mt < 4; ++mt) asm volatile("" : "+v"(negInit[mt]));

  float s[16];
#pragma unroll
  for (int e = 0; e < 16; ++e) s[e] = 0.f;

  f32x4 acc[4];
  const char* rbase = wlds + kg * 256 + r16 * 16;

#define EXPACC() do {                                                              \
    _Pragma("unroll") for (int mt = 0; mt < 4; ++mt)                               \
      _Pragma("unroll") for (int i = 0; i < 4; ++i)                                \
        s[mt * 4 + i] += fast_exp2(acc[mt][i]); } while (0)

  // One step: wait -> issue(q+3) -> [exp prev tile] -> 4 ds_read -> 16 MFMA
#define STEP(QQ, BUF, HALF, DO_ISSUE, WN, DO_EXP) do {                             \
    asm volatile("s_waitcnt vmcnt(" #WN ")" ::: "memory");                         \
    __builtin_amdgcn_sched_barrier(0);                                             \
    if (DO_ISSUE) ISSUEQ((QQ) + 3, ((BUF) + 3) & 3);                               \
    if (DO_EXP) EXPACC();                                                          \
    { const char* rb_ = rbase + (BUF) * 4096;                                      \
      bf16x8 bf_[4];                                                               \
      _Pragma("unroll") for (int k = 0; k < 4; ++k)                                \
        bf_[k] = *(const bf16x8*)(rb_ + k * 1024);                                 \
      __builtin_amdgcn_s_setprio(1);                                               \
      if ((HALF) == 0) {                                                           \
        _Pragma("unroll") for (int mt = 0; mt < 4; ++mt)                           \
          acc[mt] = __builtin_amdgcn_mfma_f32_16x16x32_bf16(afrag[mt][0], bf_[0],  \
                        negInit[mt], 0, 0, 0);                                     \
        _Pragma("unroll") for (int k = 1; k < 4; ++k)                              \
          _Pragma("unroll") for (int mt = 0; mt < 4; ++mt)                         \
            acc[mt] = __builtin_amdgcn_mfma_f32_16x16x32_bf16(afrag[mt][k], bf_[k],\
                          acc[mt], 0, 0, 0);                                       \
      } else {                                                                     \
        _Pragma("unroll") for (int k = 0; k < 4; ++k)                              \
          _Pragma("unroll") for (int mt = 0; mt < 4; ++mt)                         \
            acc[mt] = __builtin_amdgcn_mfma_f32_16x16x32_bf16(afrag[mt][4 + k],    \
                          bf_[k], acc[mt], 0, 0, 0);                               \
      }                                                                            \
      __builtin_amdgcn_s_setprio(0); }                                             \
  } while (0)

  // peeled first tile (no EXP yet)
  STEP(0, 0, 0, 1, 8, 0);
  STEP(1, 1, 1, 1, 8, 0);
  STEP(2, 2, 0, 1, 8, 1);
  STEP(3, 3, 1, 1, 8, 0);
  for (int tt = 1; tt < 15; ++tt) {
    const int q0 = tt * 4;
    STEP(q0 + 0, 0, 0, 1, 8, 1);
    STEP(q0 + 1, 1, 1, 1, 8, 0);
    STEP(q0 + 2, 2, 0, 1, 8, 1);
    STEP(q0 + 3, 3, 1, 1, 8, 0);
  }
  STEP(60, 0, 0, 1, 8, 1);   // issues quarter 63
  STEP(61, 1, 1, 0, 8, 0);
  STEP(62, 2, 0, 0, 4, 1);
  STEP(63, 3, 1, 0, 0, 0);
  EXPACC();                   // last tile

#undef STEP
#undef EXPACC
#undef ISSUEQ

  // ---- sum the 16 column-partials (lanes differing in low 4 bits) ----
#pragma unroll
  for (int d = 1; d < 16; d <<= 1)
#pragma unroll
    for (int e = 0; e < 16; ++e) s[e] += __shfl_xor(s[e], d, 64);
  if (r16 == 0) {
#pragma unroll
    for (int mt = 0; mt < 4; ++mt)
#pragma unroll
      for (int i = 0; i < 4; ++i)
        swS[w][mt * 16 + kg * 4 + i] = s[mt * 4 + i];
  }
  __syncthreads();

  // ---- final per-row loss + block reduce (wave 0 only) ----
  if (t < 64) {
    const float S = 1.f + swS[0][t] + swS[1][t] + swS[2][t] + swS[3][t];
    float loss = -logf(1.f / S + EPSV);
#pragma unroll
    for (int d = 1; d < 64; d <<= 1) loss += __shfl_xor(loss, d, 64);
    if (t == 0) blockSums[p] = loss;
  }
}

// ---------------------------------------------------------------------------
// Final: mean of 512 block sums / (512*64).  grid=1, block=256.
// ---------------------------------------------------------------------------
__global__ void cpl_final(const float* __restrict__ blockSums, float* __restrict__ out) {
  const int t = threadIdx.x;
  float s = blockSums[t] + blockSums[t + 256];
#pragma unroll
  for (int d = 1; d < 64; d <<= 1) s += __shfl_xor(s, d, 64);
  __shared__ float ps[4];
  if ((t & 63) == 0) ps[t >> 6] = s;
  __syncthreads();
  if (t == 0) out[0] = (ps[0] + ps[1] + ps[2] + ps[3]) * (1.f / 32768.f);
}

extern "C" void kernel_launch(void* const* d_in, const int* in_sizes, int n_in,
                              void* d_out, int out_size, void* d_ws, size_t ws_size,
                              hipStream_t stream) {
  const float* mainO = (const float*)d_in[0];
  const float* emaO  = (const float*)d_in[1];
  const float* label = (const float*)d_in[2];
  const float* negB  = (const float*)d_in[3];
  const float* posB  = (const float*)d_in[4];
  float* out = (float*)d_out;

  char* ws = (char*)d_ws;
  float*  blockSums = (float*)ws;                        // 2 KiB
  int*    flags     = (int*)(ws + 2048);                 // 2 KiB
  ushort* bankN     = (ushort*)(ws + 4096);              // 1 MiB
  ushort* bankP     = (ushort*)(ws + 4096 + 1048576);    // 1 MiB
  float*  posDot    = (float*)(ws + 4096 + 2097152);     // 128 KiB
  ushort* Apk       = (ushort*)(ws + 4096 + 2097152 + 131072);  // 16.78 MiB

  hipLaunchKernelGGL(cpl_prep, dim3(1088), dim3(256), 0, stream,
                     mainO, emaO, label, negB, posB, Apk, posDot, flags, bankN, bankP);
  hipLaunchKernelGGL(cpl_main, dim3(512), dim3(256), 0, stream,
                     Apk, posDot, bankN, bankP, flags, blockSums);
  hipLaunchKernelGGL(cpl_final, dim3(1), dim3(256), 0, stream, blockSums, out);
}

// Round 9
// 61.578 us; speedup vs baseline: 1.0230x; 1.0221x over previous
//
#include <hip/hip_runtime.h>

typedef __attribute__((ext_vector_type(8))) short bf16x8;
typedef __attribute__((ext_vector_type(4))) float f32x4;

#define EPSV 1e-5f
// (1/TEMP) * log2(e),  TEMP = 0.5  -> exp2-domain scale
#define SCALE 2.885390081777927f

// Must be the builtin — raw inline-asm v_exp_f32 lacks the TRANS-pipe hazard
// nop (asm is opaque to the hazard recognizer) and returns garbage (R4).
__device__ __forceinline__ float fast_exp2(float x) { return __builtin_amdgcn_exp2f(x); }

// async global->LDS DMA, 16 B per lane; LDS dest = uniform base + lane*16.
__device__ __forceinline__ void dma16(const void* g, void* l) {
  __builtin_amdgcn_global_load_lds(
      (const __attribute__((address_space(1))) unsigned*)g,
      (__attribute__((address_space(3))) unsigned*)l, 16, 0, 0);
}

__device__ __forceinline__ ushort f32_to_bf16(float f) {
  union { float f; unsigned u; } cv; cv.f = f;
  unsigned u = cv.u;
  u += 0x7FFFu + ((u >> 16) & 1u);   // round-to-nearest-even
  return (ushort)(u >> 16);
}

// ---------------------------------------------------------------------------
// Packed bank layout (bf16, pre-scaled by SCALE):
//   col-tile ct = col>>4, r16 = col&15; channel c: ks = c>>5, kg = (c>>3)&3.
//   byte addr = ct*8192 + ks*1024 + kg*256 + r16*16 + (c&7)*2
// Per wave a 512-col range is a LINEAR 256 KB stream; staged in 4 KB quarters.
// ---------------------------------------------------------------------------

// ---------------------------------------------------------------------------
// Fused prep kernel, grid = 512 + 512 + 64 = 1088 blocks, 256 threads.
// ---------------------------------------------------------------------------
__global__ __launch_bounds__(256) void cpl_prep(
    const float* __restrict__ mainO, const float* __restrict__ emaO,
    const float* __restrict__ label, const float* __restrict__ negB,
    const float* __restrict__ posB,
    ushort* __restrict__ Apk, float* __restrict__ posDot,
    int* __restrict__ flags, ushort* __restrict__ bankN, ushort* __restrict__ bankP)
{
  __shared__ ushort shU[64 * 256];   // 32 KiB
  __shared__ float  shF[4][64];
  const int bid = blockIdx.x;
  const int t = threadIdx.x;

  if (bid < 512) {
    // ---- anchor pack + pos dot: block = (b, y) ----
    const int b = bid >> 6, y = bid & 63;
    const int cg = t >> 4;            // c-offset 0..15
    const int x4 = t & 15;            // float4 index along W
    const float* mB = mainO + (((size_t)b * 256 + cg) * 64 + y) * 64 + x4 * 4;
    const float* eB = emaO  + (((size_t)b * 256 + cg) * 64 + y) * 64 + x4 * 4;
    float4 acc4 = make_float4(0.f, 0.f, 0.f, 0.f);
#pragma unroll
    for (int pass = 0; pass < 16; ++pass) {
      const int c = pass * 16 + cg;
      const float4 mv = *(const float4*)(mB + (size_t)pass * 16 * 4096);
      const float4 ev = *(const float4*)(eB + (size_t)pass * 16 * 4096);
      acc4.x += mv.x * ev.x; acc4.y += mv.y * ev.y;
      acc4.z += mv.z * ev.z; acc4.w += mv.w * ev.w;
      const float vals[4] = {mv.x, mv.y, mv.z, mv.w};
#pragma unroll
      for (int j = 0; j < 4; ++j) {
        const int x = x4 * 4 + j;
        shU[x * 256 + (c ^ ((x & 7) << 3))] = f32_to_bf16(vals[j]);
      }
    }
    // reduce pos partials over c-groups (cg bit0 = lane bit4, bit1 = lane bit5)
    acc4.x += __shfl_xor(acc4.x, 16, 64); acc4.y += __shfl_xor(acc4.y, 16, 64);
    acc4.z += __shfl_xor(acc4.z, 16, 64); acc4.w += __shfl_xor(acc4.w, 16, 64);
    acc4.x += __shfl_xor(acc4.x, 32, 64); acc4.y += __shfl_xor(acc4.y, 32, 64);
    acc4.z += __shfl_xor(acc4.z, 32, 64); acc4.w += __shfl_xor(acc4.w, 32, 64);
    if ((t & 63) < 16) *(float4*)&shF[t >> 6][(t & 15) * 4] = acc4;
    __syncthreads();
    // write packed anchors (coalesced b128)
#pragma unroll
    for (int it = 0; it < 8; ++it) {
      const int lin = it * 256 + t;          // 0..2047
      const int x = lin >> 5, c8 = lin & 31;
      const uint4 v = *(const uint4*)&shU[x * 256 + ((c8 * 8) ^ ((x & 7) << 3))];
      const int p = b * 64 + ((y >> 3) << 3) + (x >> 3);
      const int n = ((y & 7) << 3) + (x & 7);
      *(uint4*)&Apk[((size_t)p * 64 + n) * 256 + c8 * 8] = v;
    }
    if (t < 64) {
      const float pv = shF[0][t] + shF[1][t] + shF[2][t] + shF[3][t];
      const int p = b * 64 + ((y >> 3) << 3) + (t >> 3);
      const int n = ((y & 7) << 3) + (t & 7);
      posDot[p * 64 + n] = pv;
    }
  } else if (bid < 1024) {
    // ---- label mean -> flag ----
    const int p = bid - 512;
    const int b = p >> 6, pj = (p >> 3) & 7, pk = p & 7;
    const size_t base = ((size_t)b * 256 + pj * 32) * 256 + pk * 32;
    float s = 0.f;
#pragma unroll
    for (int i = 0; i < 4; ++i) {
      const int e = t * 4 + i;               // 0..1023, r=e>>5, cc=e&31
      s += label[base + (size_t)(e >> 5) * 256 + (e & 31)];
    }
#pragma unroll
    for (int d = 1; d < 64; d <<= 1) s += __shfl_xor(s, d, 64);
    if ((t & 63) == 0) shF[0][t >> 6] = s;
    __syncthreads();
    if (t == 0)
      flags[p] = ((shF[0][0] + shF[0][1] + shF[0][2] + shF[0][3]) * (1.f / 1024.f) < 0.1f) ? 1 : 0;
  } else {
    // ---- bank repack (pre-scaled by SCALE) into the packed tile layout ----
    const int bb = bid - 1024;
    const float* src = (bb < 32 ? negB : posB) + (size_t)(bb & 31) * 16384;
    ushort* dst = (bb < 32 ? bankN : bankP) + (size_t)(bb & 31) * 16384;
#pragma unroll 8
    for (int it = 0; it < 64; ++it) {
      const int lin = it * 256 + t;          // [c][posi] linear, coalesced read
      const int c = lin >> 6, posi = lin & 63;
      shU[(posi * 256 + c) ^ ((posi & 31) << 1)] = f32_to_bf16(src[lin] * SCALE);
    }
    __syncthreads();
    unsigned* dst32 = (unsigned*)dst;        // 8192 uints per slab
#pragma unroll 8
    for (int it = 0; it < 32; ++it) {
      const int pt = it >> 3, ks = it & 7;
      const int kg = t >> 6, r16 = (t >> 2) & 15, bw = t & 3;
      const int posi = pt * 16 + r16;
      const int c = ks * 32 + kg * 8 + bw * 2;
      const unsigned v = *(const unsigned*)&shU[(posi * 256 + c) ^ ((posi & 31) << 1)];
      dst32[pt * 2048 + ks * 256 + kg * 64 + r16 * 4 + bw] = v;
    }
  }
}

// ---------------------------------------------------------------------------
// Main kernel: grid=256 blocks x 512 threads (8 waves), TWO patches per block.
// Wave (q, w4): q = patch slot, w4 = col range. In shared mode (same flag)
// the q=0 waves stage B and BOTH quads consume it -> B traffic per CU halves,
// arithmetic intensity doubles (128 FLOP/B). Mismatched flags -> dual mode
// (each quad stages its own ring; LDS 128 KB). Per-step raw s_barrier (no
// waitcnt drain) + producer-counted vmcnt(8).
// ---------------------------------------------------------------------------
__global__ __launch_bounds__(512, 2) void cpl_main(
    const ushort* __restrict__ Apk, const float* __restrict__ posDot,
    const ushort* __restrict__ bankN, const ushort* __restrict__ bankP,
    const int* __restrict__ flags, float* __restrict__ blockSums)
{
  __shared__ __align__(1024) char Bsm[2 * 65536];   // 128 KiB (dual-mode max)
  __shared__ float swS[2][4][64];

  const int bid = blockIdx.x;
  const int t = threadIdx.x;
  const int w = t >> 6, q = w >> 2, w4 = w & 3, l = t & 63;
  const int r16 = l & 15, kg = l >> 4;

  const int p0 = bid * 2, p1 = bid * 2 + 1;
  const int f0 = flags[p0], f1 = flags[p1];
  const bool dual = (f0 != f1);
  const int pMine = q ? p1 : p0;
  const int fMine = q ? f1 : f0;
  const bool producer = (q == 0) || dual;

  const char* bankB = (const char*)(fMine ? bankP : bankN);
  const char* wsrc = bankB + (size_t)w4 * 262144;     // this col-range's stream
  char* wlds = Bsm + (dual ? q : 0) * 65536 + w4 * 16384;
  const int lofs = l * 16;

  // ---- A fragments: lane l holds A[mt*16+(l&15)][ks*32+(l>>4)*8 + 0..7] ----
  const ushort* Ab = Apk + (size_t)pMine * 16384;
  bf16x8 afrag[4][8];
#pragma unroll
  for (int mt = 0; mt < 4; ++mt)
#pragma unroll
    for (int ks = 0; ks < 8; ++ks)
      afrag[mt][ks] = *(const bf16x8*)(Ab + (mt * 16 + r16) * 256 + ks * 32 + kg * 8);
#pragma unroll
  for (int mt = 0; mt < 4; ++mt)
#pragma unroll
    for (int ks = 0; ks < 8; ++ks)
      asm volatile("" : "+v"(afrag[mt][ks]));

  // per-lane -pos2 init in REGISTERS (row = mt*16 + kg*4 + i), direct global
  f32x4 negInit[4];
#pragma unroll
  for (int mt = 0; mt < 4; ++mt) {
    f32x4 v = *(const f32x4*)(posDot + (size_t)pMine * 64 + mt * 16 + kg * 4);
#pragma unroll
    for (int i = 0; i < 4; ++i) negInit[mt][i] = -v[i] * SCALE;
  }
#pragma unroll
  for (int mt = 0; mt < 4; ++mt) asm volatile("" : "+v"(negInit[mt]));

  // all prologue loads retired -> vmcnt counting below starts clean
  asm volatile("s_waitcnt vmcnt(0)" ::: "memory");

#define ISSUEQ(QQ, BUF) do {                                                       \
    const char* g0_ = wsrc + (size_t)(QQ) * 4096 + lofs;                           \
    char* l0_ = wlds + (BUF) * 4096;                                               \
    _Pragma("unroll") for (int i = 0; i < 4; ++i)                                  \
      dma16(g0_ + i * 1024, l0_ + i * 1024);                                       \
  } while (0)

  if (producer) { ISSUEQ(0, 0); ISSUEQ(1, 1); ISSUEQ(2, 2); }   // 12 in flight

  float s[16];
#pragma unroll
  for (int e = 0; e < 16; ++e) s[e] = 0.f;

  f32x4 acc[4];
  const char* rbase = wlds + kg * 256 + r16 * 16;

#define EXPACC() do {                                                              \
    _Pragma("unroll") for (int mt = 0; mt < 4; ++mt)                               \
      _Pragma("unroll") for (int i = 0; i < 4; ++i)                                \
        s[mt * 4 + i] += fast_exp2(acc[mt][i]); } while (0)

  // step: [producer vmcnt] -> s_barrier -> [issue q+3] -> [exp prev] -> 16 MFMA
#define STEP(QQ, BUF, HALF, DO_ISSUE, WN, DO_EXP) do {                             \
    if (producer) { asm volatile("s_waitcnt vmcnt(" #WN ")" ::: "memory"); }       \
    __builtin_amdgcn_sched_barrier(0);                                             \
    __builtin_amdgcn_s_barrier();                                                  \
    __builtin_amdgcn_sched_barrier(0);                                             \
    if ((DO_ISSUE) && producer) ISSUEQ((QQ) + 3, ((QQ) + 3) & 3);                  \
    if (DO_EXP) EXPACC();                                                          \
    { const char* rb_ = rbase + (BUF) * 4096;                                      \
      bf16x8 bf_[4];                                                               \
      _Pragma("unroll") for (int k = 0; k < 4; ++k)                                \
        bf_[k] = *(const bf16x8*)(rb_ + k * 1024);                                 \
      __builtin_amdgcn_s_setprio(1);                                               \
      if ((HALF) == 0) {                                                           \
        _Pragma("unroll") for (int mt = 0; mt < 4; ++mt)                           \
          acc[mt] = __builtin_amdgcn_mfma_f32_16x16x32_bf16(afrag[mt][0], bf_[0],  \
                        negInit[mt], 0, 0, 0);                                     \
        _Pragma("unroll") for (int k = 1; k < 4; ++k)                              \
          _Pragma("unroll") for (int mt = 0; mt < 4; ++mt)                         \
            acc[mt] = __builtin_amdgcn_mfma_f32_16x16x32_bf16(afrag[mt][k], bf_[k],\
                          acc[mt], 0, 0, 0);                                       \
      } else {                                                                     \
        _Pragma("unroll") for (int k = 0; k < 4; ++k)                              \
          _Pragma("unroll") for (int mt = 0; mt < 4; ++mt)                         \
            acc[mt] = __builtin_amdgcn_mfma_f32_16x16x32_bf16(afrag[mt][4 + k],    \
                          bf_[k], acc[mt], 0, 0, 0);                               \
      }                                                                            \
      __builtin_amdgcn_s_setprio(0); }                                             \
  } while (0)

  STEP(0, 0, 0, 1, 8, 0);
  STEP(1, 1, 1, 1, 8, 0);
  for (int tt = 1; tt <= 29; ++tt) {
    STEP(2 * tt,     (2 * tt) & 3,     0, 1, 8, 1);
    STEP(2 * tt + 1, (2 * tt + 1) & 3, 1, 1, 8, 0);
  }
  STEP(60, 0, 0, 1, 8, 1);   // issues quarter 63
  STEP(61, 1, 1, 0, 8, 0);
  STEP(62, 2, 0, 0, 4, 1);
  STEP(63, 3, 1, 0, 0, 0);
  EXPACC();                   // last tile

#undef STEP
#undef EXPACC
#undef ISSUEQ

  // ---- sum the 16 column-partials (lanes differing in low 4 bits) ----
#pragma unroll
  for (int d = 1; d < 16; d <<= 1)
#pragma unroll
    for (int e = 0; e < 16; ++e) s[e] += __shfl_xor(s[e], d, 64);
  if (r16 == 0) {
#pragma unroll
    for (int mt = 0; mt < 4; ++mt)
#pragma unroll
      for (int i = 0; i < 4; ++i)
        swS[q][w4][mt * 16 + kg * 4 + i] = s[mt * 4 + i];
  }
  __syncthreads();

  // ---- final per-row loss + per-patch reduce (waves 0,1 = patches 0,1) ----
  if (t < 128) {
    const int q2 = t >> 6, row = t & 63;
    const float S = 1.f + swS[q2][0][row] + swS[q2][1][row]
                        + swS[q2][2][row] + swS[q2][3][row];
    float loss = -logf(1.f / S + EPSV);
#pragma unroll
    for (int d = 1; d < 64; d <<= 1) loss += __shfl_xor(loss, d, 64);
    if (row == 0) blockSums[bid * 2 + q2] = loss;
  }
}

// ---------------------------------------------------------------------------
// Final: mean of 512 block sums / (512*64).  grid=1, block=256.
// ---------------------------------------------------------------------------
__global__ void cpl_final(const float* __restrict__ blockSums, float* __restrict__ out) {
  const int t = threadIdx.x;
  float s = blockSums[t] + blockSums[t + 256];
#pragma unroll
  for (int d = 1; d < 64; d <<= 1) s += __shfl_xor(s, d, 64);
  __shared__ float ps[4];
  if ((t & 63) == 0) ps[t >> 6] = s;
  __syncthreads();
  if (t == 0) out[0] = (ps[0] + ps[1] + ps[2] + ps[3]) * (1.f / 32768.f);
}

extern "C" void kernel_launch(void* const* d_in, const int* in_sizes, int n_in,
                              void* d_out, int out_size, void* d_ws, size_t ws_size,
                              hipStream_t stream) {
  const float* mainO = (const float*)d_in[0];
  const float* emaO  = (const float*)d_in[1];
  const float* label = (const float*)d_in[2];
  const float* negB  = (const float*)d_in[3];
  const float* posB  = (const float*)d_in[4];
  float* out = (float*)d_out;

  char* ws = (char*)d_ws;
  float*  blockSums = (float*)ws;                        // 2 KiB
  int*    flags     = (int*)(ws + 2048);                 // 2 KiB
  ushort* bankN     = (ushort*)(ws + 4096);              // 1 MiB
  ushort* bankP     = (ushort*)(ws + 4096 + 1048576);    // 1 MiB
  float*  posDot    = (float*)(ws + 4096 + 2097152);     // 128 KiB
  ushort* Apk       = (ushort*)(ws + 4096 + 2097152 + 131072);  // 16.78 MiB

  hipLaunchKernelGGL(cpl_prep, dim3(1088), dim3(256), 0, stream,
                     mainO, emaO, label, negB, posB, Apk, posDot, flags, bankN, bankP);
  hipLaunchKernelGGL(cpl_main, dim3(256), dim3(512), 0, stream,
                     Apk, posDot, bankN, bankP, flags, blockSums);
  hipLaunchKernelGGL(cpl_final, dim3(1), dim3(256), 0, stream, blockSums, out);
}